// Round 5
// baseline (107.197 us; speedup 1.0000x reference)
//
#include <hip/hip_runtime.h>
#include <hip/hip_fp16.h>

#define B 32
#define O 64
#define M 128
#define H 4
#define E 64
#define SC 2.88539008177792681f     // 2*log2(e): tanh(x) = 1 - 2*rcp(1+exp2(SC*x))
#define LOG2E 1.44269504088896341f

#if __has_builtin(__builtin_amdgcn_exp2f)
#define EXP2F(x) __builtin_amdgcn_exp2f(x)
#else
#define EXP2F(x) __exp2f(x)
#endif

__device__ __forceinline__ float rl(float v, int lane) {
    return __uint_as_float(__builtin_amdgcn_readlane(__float_as_uint(v), lane));
}
__device__ __forceinline__ unsigned pk2h(float a, float b) {
    return (unsigned)__half_as_ushort(__float2half_rn(a)) |
           ((unsigned)__half_as_ushort(__float2half_rn(b)) << 16);
}

// ============ prep: blocks 0..31 convert ctx(->T,x SC,fp16) + mem(fp16);
//              blocks 32..543: q_all = (query@W_ch + b_ch)*SC, 4 rows/block ====
__global__ __launch_bounds__(256) void prep_kernel(
    const float* __restrict__ query, const float* __restrict__ context,
    const float* __restrict__ memory, const float* __restrict__ W_ch,
    const float* __restrict__ b_ch,
    __half* __restrict__ ctx_T, __half* __restrict__ mem_h, float* __restrict__ q_all)
{
    __shared__ float s[128 * 68];          // conv path: ctx staged stride-68
    const int t = threadIdx.x, blk = blockIdx.x;

    if (blk < 32) {
        const int b = blk;
        const float* ctx = context + b * (M * E);
        #pragma unroll
        for (int i = 0; i < 8; ++i) {       // stage ctx coalesced
            int idx = i * 1024 + t * 4;
            float4 v = *(const float4*)(ctx + idx);
            int m = idx >> 6, e = idx & 63;
            *(float4*)(&s[m * 68 + e]) = v;
        }
        // memory -> fp16 (no transpose), coalesced 8B stores
        {
            const float* mem = memory + b * (M * E);
            __half* mh = mem_h + (size_t)b * (M * E);
            #pragma unroll
            for (int i = 0; i < 8; ++i) {
                int idx = i * 1024 + t * 4;
                float4 v = *(const float4*)(mem + idx);
                *(uint2*)(mh + idx) = make_uint2(pk2h(v.x, v.y), pk2h(v.z, v.w));
            }
        }
        __syncthreads();
        // transpose out: thread -> (e = t>>2, m-block = (t&3)*32), 64B store
        {
            int e = t >> 2, mb = (t & 3) * 32;
            uint4 o[4];
            #pragma unroll
            for (int qd = 0; qd < 4; ++qd) {
                unsigned u[4];
                #pragma unroll
                for (int k = 0; k < 4; ++k) {
                    int m0 = mb + qd * 8 + 2 * k;
                    u[k] = pk2h(s[m0 * 68 + e] * SC, s[(m0 + 1) * 68 + e] * SC);
                }
                o[qd] = make_uint4(u[0], u[1], u[2], u[3]);
            }
            uint4* dst = (uint4*)(ctx_T + (size_t)b * (E * M) + e * M + mb);
            dst[0] = o[0]; dst[1] = o[1]; dst[2] = o[2]; dst[3] = o[3];
        }
    } else {
        const int r0 = (blk - 32) * 4;      // 4 query rows (bo indices)
        // stage 4x64 query transposed into s[k*4+r]
        s[t] = query[(r0 + (t & 3)) * 64 + (t >> 2)];
        __syncthreads();
        float bc = b_ch[t];
        float a0 = bc, a1 = bc, a2 = bc, a3 = bc;
        #pragma unroll 8
        for (int k = 0; k < 64; ++k) {
            float4 qv = *(const float4*)(&s[k * 4]);   // uniform ds_read_b128
            float wv = W_ch[k * 256 + t];
            a0 = fmaf(qv.x, wv, a0);
            a1 = fmaf(qv.y, wv, a1);
            a2 = fmaf(qv.z, wv, a2);
            a3 = fmaf(qv.w, wv, a3);
        }
        float* qa = q_all + (size_t)r0 * 256 + t;
        qa[0] = a0 * SC; qa[256] = a1 * SC; qa[512] = a2 * SC; qa[768] = a3 * SC;
    }
}

// ============ main: per (b,o) block. LDS = 22.5 KB -> 7 blocks/CU (87% occ) ====
__global__ __launch_bounds__(256) void attn_main(
    const __half* __restrict__ ctx_T, const __half* __restrict__ mem_h,
    const float* __restrict__ q_all, const float* __restrict__ w_logit,
    const float* __restrict__ b_logit, const float* __restrict__ temp,
    __half* __restrict__ heads_h)
{
    __shared__ __half s_ctx[E * M];      // [e][m] fp16 prescaled, 16 KB
    __shared__ float  s_prob[M * H];     // [m][h]  2 KB
    __shared__ float  s_part[H * 4 * E]; // [h][wave][e] 4 KB

    const int t = threadIdx.x, lane = t & 63, w = t >> 6;
    const int bo = blockIdx.x, b = bo >> 6;

    // stage ctx_T[b] only (16 KB, dwordx4); memory is read from L2 later
    {
        const uint4* g1 = (const uint4*)(ctx_T + (size_t)b * (E * M));
        uint4* l1 = (uint4*)s_ctx;
        #pragma unroll
        for (int p = 0; p < 4; ++p)
            l1[p * 256 + t] = g1[p * 256 + t];
    }
    float qv  = q_all[bo * 256 + t];    // prescaled by SC
    float wl  = w_logit[lane];
    float we2 = 2.0f * wl;
    float sumw = wl;
    #pragma unroll
    for (int sft = 1; sft < 64; sft <<= 1) sumw += __shfl_xor(sumw, sft);
    const float bl  = b_logit[0];
    const float lsc = LOG2E / temp[0];
    __syncthreads();

    // tanh+logit: wave w = head, lane covers m = 2*lane, 2*lane+1
    float acc0 = 0.f, acc1 = 0.f;
    const __half2* c2p = (const __half2*)s_ctx;
    #pragma unroll 8
    for (int e = 0; e < 64; ++e) {
        float2 cf = __half22float2(c2p[e * 64 + lane]);
        float qe = rl(qv, e);
        float w2 = rl(we2, e);
        float r0 = __builtin_amdgcn_rcpf(1.0f + EXP2F(cf.x + qe));
        float r1 = __builtin_amdgcn_rcpf(1.0f + EXP2F(cf.y + qe));
        acc0 = fmaf(w2, r0, acc0);   // acc = sum we*2*r ; logit = sumw - acc
        acc1 = fmaf(w2, r1, acc1);
    }
    float l0 = (sumw - acc0 + bl) * lsc;
    float l1 = (sumw - acc1 + bl) * lsc;
    float mx = fmaxf(l0, l1);
    #pragma unroll
    for (int sft = 1; sft < 64; sft <<= 1) mx = fmaxf(mx, __shfl_xor(mx, sft));
    float e0 = EXP2F(l0 - mx);
    float e1 = EXP2F(l1 - mx);
    float sum = e0 + e1;
    #pragma unroll
    for (int sft = 1; sft < 64; sft <<= 1) sum += __shfl_xor(sum, sft);
    float rs = __builtin_amdgcn_rcpf(sum);
    s_prob[(2 * lane) * H + w]     = e0 * rs;
    s_prob[(2 * lane + 1) * H + w] = e1 * rs;
    __syncthreads();

    // cooperative heads: wave w covers m in [32w,32w+32), all 4 heads; lane = e
    // memory read from L2 (fp16, coalesced 128B/wave-load, ~33MB device-wide)
    float h0 = 0.f, h1 = 0.f, h2 = 0.f, h3 = 0.f;
    {
        const __half* mem = mem_h + (size_t)b * (M * E) + lane;
        #pragma unroll 8
        for (int i = 0; i < 32; ++i) {
            int m = 32 * w + i;
            float4 p = *(const float4*)(&s_prob[m * 4]);    // uniform b128
            float mv = __half2float(mem[m * 64]);
            h0 = fmaf(p.x, mv, h0);
            h1 = fmaf(p.y, mv, h1);
            h2 = fmaf(p.z, mv, h2);
            h3 = fmaf(p.w, mv, h3);
        }
    }
    s_part[0 * 256 + w * 64 + lane] = h0;
    s_part[1 * 256 + w * 64 + lane] = h1;
    s_part[2 * 256 + w * 64 + lane] = h2;
    s_part[3 * 256 + w * 64 + lane] = h3;
    __syncthreads();
    // final: thread t -> (h = w, e = lane); leaky relu; fp16 store
    float hv = s_part[w * 256 + lane] + s_part[w * 256 + 64 + lane]
             + s_part[w * 256 + 128 + lane] + s_part[w * 256 + 192 + lane];
    hv = (hv > 0.f) ? hv : 0.01f * hv;
    heads_h[(size_t)bo * 256 + t] = __float2half_rn(hv);
}

// ============ post: out = heads @ W_rh + b_rh ; 4 rows/block, 512 blocks ====
__global__ __launch_bounds__(256) void post_kernel(
    const __half* __restrict__ heads_h, const float* __restrict__ W_rh,
    const float* __restrict__ b_rh, float* __restrict__ out)
{
    __shared__ __half s_h[4 * 256];     // 2KB
    const int t = threadIdx.x, lane = t & 63, r = t >> 6;   // wave = row
    const int r0 = blockIdx.x * 4;
    ((uint4*)s_h)[t & 127] = ((const uint4*)(heads_h + (size_t)r0 * 256))[t & 127];
    __syncthreads();
    const __half2* hr = (const __half2*)(s_h + r * 256);
    const float* Wp = W_rh + lane;
    float acc = 0.f;
    #pragma unroll 8
    for (int jp = 0; jp < 128; ++jp) {
        float2 hh = __half22float2(hr[jp]);    // uniform per wave
        acc = fmaf(hh.x, Wp[(2 * jp) * 64], acc);
        acc = fmaf(hh.y, Wp[(2 * jp + 1) * 64], acc);
    }
    out[(size_t)(r0 + r) * 64 + lane] = acc + b_rh[lane];
}

extern "C" void kernel_launch(void* const* d_in, const int* in_sizes, int n_in,
                              void* d_out, int out_size, void* d_ws, size_t ws_size,
                              hipStream_t stream) {
    const float* query   = (const float*)d_in[0];
    const float* context = (const float*)d_in[1];
    const float* memory  = (const float*)d_in[2];
    const float* W_ch    = (const float*)d_in[3];
    const float* b_ch    = (const float*)d_in[4];
    const float* w_logit = (const float*)d_in[5];
    const float* b_logit = (const float*)d_in[6];
    const float* W_rh    = (const float*)d_in[7];
    const float* b_rh    = (const float*)d_in[8];
    const float* temp    = (const float*)d_in[9];
    float* out = (float*)d_out;

    // workspace carve: ctx_T 512K | mem_h 512K | q_all 2M | heads_h 1M  (4MB total)
    __half* ctx_T   = (__half*)d_ws;
    __half* mem_h   = ctx_T + (size_t)B * E * M;
    float*  q_all   = (float*)(mem_h + (size_t)B * M * E);
    __half* heads_h = (__half*)(q_all + (size_t)B * O * H * E);

    prep_kernel<<<544, 256, 0, stream>>>(query, context, memory, W_ch, b_ch,
                                         ctx_T, mem_h, q_all);
    attn_main<<<B * O, 256, 0, stream>>>(ctx_T, mem_h, q_all, w_logit,
                                         b_logit, temp, heads_h);
    post_kernel<<<512, 256, 0, stream>>>(heads_h, W_rh, b_rh, out);
}